// Round 1
// baseline (1239.166 us; speedup 1.0000x reference)
//
#include <hip/hip_runtime.h>

// AttentionReadoutAtom: scores = x@w + b; attn = softmax(scores, axis=0);
// out[seg] += x[i] * attn[i] for seg = labels[i].
// N = 500000, IN_DIM = 128, NUM_SEGMENTS = 50000.
//
// ws layout (floats):
//   [0]            : invZ  (1/sum(exp(scores)))
//   [64 .. 64+N)   : scores
//   [64+N .. )     : per-block exp-sum partials (nblocks entries)

#define BLOCK 256

// One row per 32-lane group; lane g covers cols [4g, 4g+4).
__global__ __launch_bounds__(BLOCK) void k_scores(const float* __restrict__ x,
                                                  const float* __restrict__ w,
                                                  const float* __restrict__ b,
                                                  float* __restrict__ scores,
                                                  float* __restrict__ partials,
                                                  int n) {
    const int g = threadIdx.x & 31;
    const int row = (int)((blockIdx.x * (unsigned)BLOCK + threadIdx.x) >> 5);

    float e = 0.0f;
    if (row < n) {
        const float4 wv = ((const float4*)w)[g];
        const float4 xv = ((const float4*)x)[(size_t)row * 32 + g];
        float p = xv.x * wv.x + xv.y * wv.y + xv.z * wv.z + xv.w * wv.w;
        p += __shfl_down(p, 16, 32);
        p += __shfl_down(p, 8, 32);
        p += __shfl_down(p, 4, 32);
        p += __shfl_down(p, 2, 32);
        p += __shfl_down(p, 1, 32);
        if (g == 0) {
            const float s = p + b[0];
            scores[row] = s;
            e = expf(s);
        }
    }

    // Deterministic per-block partial sum of exp(scores): 8 group leaders.
    __shared__ float se[BLOCK / 32];
    if ((threadIdx.x & 31) == 0) se[threadIdx.x >> 5] = e;
    __syncthreads();
    if (threadIdx.x == 0) {
        float sum = 0.0f;
#pragma unroll
        for (int i = 0; i < BLOCK / 32; ++i) sum += se[i];
        partials[blockIdx.x] = sum;
    }
}

// Single-block reduction of per-block partials -> invZ.
__global__ __launch_bounds__(BLOCK) void k_reduce_z(const float* __restrict__ partials,
                                                    int nparts,
                                                    float* __restrict__ inv_z) {
    float s = 0.0f;
    for (int i = threadIdx.x; i < nparts; i += BLOCK) s += partials[i];
#pragma unroll
    for (int off = 32; off > 0; off >>= 1) s += __shfl_down(s, off, 64);
    __shared__ float sw[BLOCK / 64];
    if ((threadIdx.x & 63) == 0) sw[threadIdx.x >> 6] = s;
    __syncthreads();
    if (threadIdx.x == 0) {
        float z = 0.0f;
#pragma unroll
        for (int i = 0; i < BLOCK / 64; ++i) z += sw[i];
        *inv_z = 1.0f / z;
    }
}

// One row per 32-lane group; scatter x[i]*attn[i] into out[labels[i]].
__global__ __launch_bounds__(BLOCK) void k_scatter(const float* __restrict__ x,
                                                   const float* __restrict__ scores,
                                                   const int* __restrict__ labels,
                                                   const float* __restrict__ inv_zp,
                                                   float* __restrict__ out,
                                                   int n) {
    const int g = threadIdx.x & 31;
    const int row = (int)((blockIdx.x * (unsigned)BLOCK + threadIdx.x) >> 5);
    if (row >= n) return;

    const float inv_z = *inv_zp;
    const float a = expf(scores[row]) * inv_z;
    const float4 xv = ((const float4*)x)[(size_t)row * 32 + g];
    const int seg = labels[row];
    float* o = out + (size_t)seg * 128 + (size_t)g * 4;
    unsafeAtomicAdd(o + 0, xv.x * a);
    unsafeAtomicAdd(o + 1, xv.y * a);
    unsafeAtomicAdd(o + 2, xv.z * a);
    unsafeAtomicAdd(o + 3, xv.w * a);
}

extern "C" void kernel_launch(void* const* d_in, const int* in_sizes, int n_in,
                              void* d_out, int out_size, void* d_ws, size_t ws_size,
                              hipStream_t stream) {
    const float* x      = (const float*)d_in[0];
    const int*   labels = (const int*)d_in[1];
    const float* w      = (const float*)d_in[2];
    const float* b      = (const float*)d_in[3];
    float* out = (float*)d_out;

    const int n = in_sizes[1];              // 500000 rows
    const int nblocks = (n * 32 + BLOCK - 1) / BLOCK;  // 62500

    float* inv_z    = (float*)d_ws;
    float* scores   = (float*)d_ws + 64;
    float* partials = scores + n;

    hipMemsetAsync(d_out, 0, (size_t)out_size * sizeof(float), stream);
    k_scores<<<nblocks, BLOCK, 0, stream>>>(x, w, b, scores, partials, n);
    k_reduce_z<<<1, BLOCK, 0, stream>>>(partials, nblocks, inv_z);
    k_scatter<<<nblocks, BLOCK, 0, stream>>>(x, scores, labels, inv_z, out, n);
}

// Round 2
// 536.234 us; speedup vs baseline: 2.3109x; 2.3109x over previous
//
#include <hip/hip_runtime.h>

// AttentionReadoutAtom: scores = x@w + b; attn = softmax(scores, axis=0);
// out[seg] = sum_{i: labels[i]==seg} x[i] * attn[i].
// N = 500000, IN_DIM = 128, NUM_SEGMENTS = 50000.
//
// Strategy: no f32 atomics on out (R1 showed 64M scatter atomics cost 1 GB of
// 16B-granular TCC write traffic -> 840 us). Instead: CSR bucket rows by
// segment, then gather-sum one wave per segment.
//
// ws layout (floats / ints, all 4B):
//   [0]                       invZ
//   [64 .. 64+N)              e_i = exp(score_i)      (N floats)
//   [64+N .. +NBS)            per-block exp partials  (NBS floats)
//   then: hist[S], offsets[S+1], cursor[S], bucket[N] (ints)

#define NBS 4096   // k_scores_hist grid

__global__ __launch_bounds__(256) void k_scores_hist(const float* __restrict__ x,
                                                     const float* __restrict__ w,
                                                     const float* __restrict__ b,
                                                     const int* __restrict__ labels,
                                                     float* __restrict__ evals,
                                                     float* __restrict__ partials,
                                                     int* __restrict__ hist,
                                                     int n) {
    const int g = threadIdx.x & 31;          // lane within 32-lane row group
    const int grp = threadIdx.x >> 5;        // 8 groups per block
    const float4 wv = ((const float4*)w)[g];
    const float bias = b[0];

    float esum = 0.0f;
    for (int row = blockIdx.x * 8 + grp; row < n; row += gridDim.x * 8) {
        const float4 xv = ((const float4*)x)[(size_t)row * 32 + g];
        float p = xv.x * wv.x + xv.y * wv.y + xv.z * wv.z + xv.w * wv.w;
        p += __shfl_down(p, 16, 32);
        p += __shfl_down(p, 8, 32);
        p += __shfl_down(p, 4, 32);
        p += __shfl_down(p, 2, 32);
        p += __shfl_down(p, 1, 32);
        if (g == 0) {
            const float e = expf(p + bias);
            evals[row] = e;
            esum += e;
            atomicAdd(&hist[labels[row]], 1);
        }
    }

    // deterministic block reduction of esum
#pragma unroll
    for (int off = 32; off > 0; off >>= 1) esum += __shfl_down(esum, off, 64);
    __shared__ float sw[4];
    if ((threadIdx.x & 63) == 0) sw[threadIdx.x >> 6] = esum;
    __syncthreads();
    if (threadIdx.x == 0)
        partials[blockIdx.x] = sw[0] + sw[1] + sw[2] + sw[3];
}

// Single block: (A) reduce partials -> invZ; (B) exclusive scan hist -> offsets, cursor.
__global__ __launch_bounds__(1024) void k_mid(const float* __restrict__ partials,
                                              int nparts,
                                              float* __restrict__ inv_z,
                                              const int* __restrict__ hist,
                                              int* __restrict__ offsets,
                                              int* __restrict__ cursor,
                                              int S, int n) {
    // A: Z reduction
    float s = 0.0f;
    for (int i = threadIdx.x; i < nparts; i += 1024) s += partials[i];
#pragma unroll
    for (int off = 32; off > 0; off >>= 1) s += __shfl_down(s, off, 64);
    __shared__ float fw[16];
    if ((threadIdx.x & 63) == 0) fw[threadIdx.x >> 6] = s;
    __syncthreads();
    if (threadIdx.x == 0) {
        float z = 0.0f;
#pragma unroll
        for (int i = 0; i < 16; ++i) z += fw[i];
        *inv_z = 1.0f / z;
    }

    // B: exclusive scan of hist[S]
    __shared__ int ssum[1024];
    const int chunk = (S + 1023) / 1024;
    const int lo = threadIdx.x * chunk;
    const int hi = min(S, lo + chunk);
    int local = 0;
    for (int i = lo; i < hi; ++i) local += hist[i];
    ssum[threadIdx.x] = local;
    __syncthreads();
    int val = local;
    for (int off = 1; off < 1024; off <<= 1) {
        const int t = (threadIdx.x >= off) ? ssum[threadIdx.x - off] : 0;
        __syncthreads();
        val += t;
        ssum[threadIdx.x] = val;
        __syncthreads();
    }
    int run = val - local;  // exclusive prefix
    for (int i = lo; i < hi; ++i) {
        offsets[i] = run;
        cursor[i] = run;
        run += hist[i];
    }
    if (threadIdx.x == 0) offsets[S] = n;
}

__global__ __launch_bounds__(256) void k_fill(const int* __restrict__ labels,
                                              int* __restrict__ cursor,
                                              int* __restrict__ bucket,
                                              int n) {
    const int i = blockIdx.x * 256 + threadIdx.x;
    if (i < n) {
        const int pos = atomicAdd(&cursor[labels[i]], 1);
        bucket[pos] = i;
    }
}

// One 64-lane wave per segment; lane owns 2 columns (float2).
__global__ __launch_bounds__(256) void k_gather(const float* __restrict__ x,
                                                const float* __restrict__ evals,
                                                const int* __restrict__ bucket,
                                                const int* __restrict__ offsets,
                                                const float* __restrict__ inv_zp,
                                                float* __restrict__ out,
                                                int S) {
    const int lane = threadIdx.x & 63;
    const int seg = blockIdx.x * 4 + (threadIdx.x >> 6);
    if (seg >= S) return;

    const float inv_z = *inv_zp;
    const int start = offsets[seg];
    const int end = offsets[seg + 1];
    const float2* x2 = (const float2*)x;

    float2 acc = {0.0f, 0.0f};
    for (int base = start; base < end; base += 64) {
        const int cnt = min(64, end - base);
        // per-lane prefetch of row index and attention weight, broadcast via shfl
        int myrow = 0;
        float myw = 0.0f;
        if (lane < cnt) {
            myrow = bucket[base + lane];
            myw = evals[myrow] * inv_z;
        }
        for (int j = 0; j < cnt; ++j) {
            const int row = __shfl(myrow, j, 64);
            const float a = __shfl(myw, j, 64);
            const float2 xv = x2[(size_t)row * 64 + lane];
            acc.x += xv.x * a;
            acc.y += xv.y * a;
        }
    }
    ((float2*)out)[(size_t)seg * 64 + lane] = acc;
}

extern "C" void kernel_launch(void* const* d_in, const int* in_sizes, int n_in,
                              void* d_out, int out_size, void* d_ws, size_t ws_size,
                              hipStream_t stream) {
    const float* x      = (const float*)d_in[0];
    const int*   labels = (const int*)d_in[1];
    const float* w      = (const float*)d_in[2];
    const float* b      = (const float*)d_in[3];
    float* out = (float*)d_out;

    const int n = in_sizes[1];        // 500000
    const int S = out_size / 128;     // 50000

    float* inv_z    = (float*)d_ws;
    float* evals    = (float*)d_ws + 64;
    float* partials = evals + n;
    int* hist    = (int*)(partials + NBS);
    int* offsets = hist + S;          // S+1 entries
    int* cursor  = offsets + S + 1;
    int* bucket  = cursor + S;

    hipMemsetAsync(hist, 0, (size_t)S * sizeof(int), stream);
    k_scores_hist<<<NBS, 256, 0, stream>>>(x, w, b, labels, evals, partials, hist, n);
    k_mid<<<1, 1024, 0, stream>>>(partials, NBS, inv_z, hist, offsets, cursor, S, n);
    k_fill<<<(n + 255) / 256, 256, 0, stream>>>(labels, cursor, bucket, n);
    k_gather<<<(S + 3) / 4, 256, 0, stream>>>(x, evals, bucket, offsets, inv_z, out, S);
}

// Round 3
// 529.669 us; speedup vs baseline: 2.3395x; 1.0124x over previous
//
#include <hip/hip_runtime.h>

// AttentionReadoutAtom: scores = x@w + b; attn = softmax(scores, axis=0);
// out[seg] = sum_{i: labels[i]==seg} x[i] * attn[i].
// N = 500000, IN_DIM = 128, NUM_SEGMENTS = 50000.
//
// R2 -> R3: k_gather restructured. Old: 1 wave/segment, rows processed one at
// a time via serialized shfl-broadcast (1 row of MLP per wave, latency-bound
// on random 512B fetches). New: wave = 4 sub-groups x 16 lanes; each sub-group
// owns a different row concurrently (lane loads 2x float4 = 32B); 4 rows in
// flight per wave, zero serialized broadcasts; 16 shfl_xor reduction at end.
// Also dropped the d_out memset (gather writes every output element).
//
// ws layout (4B units):
//   [0] invZ | [64..64+N) evals | partials[NBS] | hist[S] | offsets[S+1]
//   | cursor[S] | bucket[N]

#define NBS 4096

__global__ __launch_bounds__(256) void k_scores_hist(const float* __restrict__ x,
                                                     const float* __restrict__ w,
                                                     const float* __restrict__ b,
                                                     const int* __restrict__ labels,
                                                     float* __restrict__ evals,
                                                     float* __restrict__ partials,
                                                     int* __restrict__ hist,
                                                     int n) {
    const int g = threadIdx.x & 31;          // lane within 32-lane row group
    const int grp = threadIdx.x >> 5;        // 8 groups per block
    const float4 wv = ((const float4*)w)[g];
    const float bias = b[0];

    float esum = 0.0f;
    for (int row = blockIdx.x * 8 + grp; row < n; row += gridDim.x * 8) {
        const float4 xv = ((const float4*)x)[(size_t)row * 32 + g];
        float p = xv.x * wv.x + xv.y * wv.y + xv.z * wv.z + xv.w * wv.w;
        p += __shfl_down(p, 16, 32);
        p += __shfl_down(p, 8, 32);
        p += __shfl_down(p, 4, 32);
        p += __shfl_down(p, 2, 32);
        p += __shfl_down(p, 1, 32);
        if (g == 0) {
            const float e = expf(p + bias);
            evals[row] = e;
            esum += e;
            atomicAdd(&hist[labels[row]], 1);
        }
    }

    // deterministic block reduction of esum
#pragma unroll
    for (int off = 32; off > 0; off >>= 1) esum += __shfl_down(esum, off, 64);
    __shared__ float sw[4];
    if ((threadIdx.x & 63) == 0) sw[threadIdx.x >> 6] = esum;
    __syncthreads();
    if (threadIdx.x == 0)
        partials[blockIdx.x] = sw[0] + sw[1] + sw[2] + sw[3];
}

// Single block: (A) reduce partials -> invZ; (B) exclusive scan hist -> offsets, cursor.
__global__ __launch_bounds__(1024) void k_mid(const float* __restrict__ partials,
                                              int nparts,
                                              float* __restrict__ inv_z,
                                              const int* __restrict__ hist,
                                              int* __restrict__ offsets,
                                              int* __restrict__ cursor,
                                              int S, int n) {
    float s = 0.0f;
    for (int i = threadIdx.x; i < nparts; i += 1024) s += partials[i];
#pragma unroll
    for (int off = 32; off > 0; off >>= 1) s += __shfl_down(s, off, 64);
    __shared__ float fw[16];
    if ((threadIdx.x & 63) == 0) fw[threadIdx.x >> 6] = s;
    __syncthreads();
    if (threadIdx.x == 0) {
        float z = 0.0f;
#pragma unroll
        for (int i = 0; i < 16; ++i) z += fw[i];
        *inv_z = 1.0f / z;
    }

    __shared__ int ssum[1024];
    const int chunk = (S + 1023) / 1024;
    const int lo = threadIdx.x * chunk;
    const int hi = min(S, lo + chunk);
    int local = 0;
    for (int i = lo; i < hi; ++i) local += hist[i];
    ssum[threadIdx.x] = local;
    __syncthreads();
    int val = local;
    for (int off = 1; off < 1024; off <<= 1) {
        const int t = (threadIdx.x >= off) ? ssum[threadIdx.x - off] : 0;
        __syncthreads();
        val += t;
        ssum[threadIdx.x] = val;
        __syncthreads();
    }
    int run = val - local;  // exclusive prefix
    for (int i = lo; i < hi; ++i) {
        offsets[i] = run;
        cursor[i] = run;
        run += hist[i];
    }
    if (threadIdx.x == 0) offsets[S] = n;
}

__global__ __launch_bounds__(256) void k_fill(const int* __restrict__ labels,
                                              int* __restrict__ cursor,
                                              int* __restrict__ bucket,
                                              int n) {
    const int i = blockIdx.x * 256 + threadIdx.x;
    if (i < n) {
        const int pos = atomicAdd(&cursor[labels[i]], 1);
        bucket[pos] = i;
    }
}

// One 64-lane wave per segment. Wave = 4 sub-groups x 16 lanes; sub-group s
// processes rows start+s, start+s+4, ... Each lane loads float4 slots
// {col, col+16} of its row (2x 256B coalesced transactions per sub-group).
// Cross-sub reduction via shfl_xor(16), shfl_xor(32); sub 0 writes the row.
__global__ __launch_bounds__(256) void k_gather(const float* __restrict__ x,
                                                const float* __restrict__ evals,
                                                const int* __restrict__ bucket,
                                                const int* __restrict__ offsets,
                                                const float* __restrict__ inv_zp,
                                                float* __restrict__ out,
                                                int S) {
    const int lane = threadIdx.x & 63;
    const int seg = blockIdx.x * 4 + (threadIdx.x >> 6);
    if (seg >= S) return;
    const int sub = lane >> 4;   // 0..3: row slot
    const int col = lane & 15;   // float4 slot within row half

    const float inv_z = *inv_zp;
    const int start = offsets[seg];
    const int end = offsets[seg + 1];
    const float4* x4 = (const float4*)x;   // 32 float4 per row

    float4 a0 = {0.f, 0.f, 0.f, 0.f};
    float4 a1 = {0.f, 0.f, 0.f, 0.f};
    for (int r = start + sub; r < end; r += 4) {
        const int row = bucket[r];
        const float a = evals[row] * inv_z;
        const float4 v0 = x4[(size_t)row * 32 + col];
        const float4 v1 = x4[(size_t)row * 32 + 16 + col];
        a0.x += v0.x * a; a0.y += v0.y * a; a0.z += v0.z * a; a0.w += v0.w * a;
        a1.x += v1.x * a; a1.y += v1.y * a; a1.z += v1.z * a; a1.w += v1.w * a;
    }

    // reduce across the 4 sub-groups (lanes with equal col)
#pragma unroll
    for (int m = 16; m <= 32; m <<= 1) {
        a0.x += __shfl_xor(a0.x, m, 64);
        a0.y += __shfl_xor(a0.y, m, 64);
        a0.z += __shfl_xor(a0.z, m, 64);
        a0.w += __shfl_xor(a0.w, m, 64);
        a1.x += __shfl_xor(a1.x, m, 64);
        a1.y += __shfl_xor(a1.y, m, 64);
        a1.z += __shfl_xor(a1.z, m, 64);
        a1.w += __shfl_xor(a1.w, m, 64);
    }
    if (sub == 0) {
        float4* o4 = (float4*)out;
        o4[(size_t)seg * 32 + col] = a0;
        o4[(size_t)seg * 32 + 16 + col] = a1;
    }
}

extern "C" void kernel_launch(void* const* d_in, const int* in_sizes, int n_in,
                              void* d_out, int out_size, void* d_ws, size_t ws_size,
                              hipStream_t stream) {
    const float* x      = (const float*)d_in[0];
    const int*   labels = (const int*)d_in[1];
    const float* w      = (const float*)d_in[2];
    const float* b      = (const float*)d_in[3];
    float* out = (float*)d_out;

    const int n = in_sizes[1];        // 500000
    const int S = out_size / 128;     // 50000

    float* inv_z    = (float*)d_ws;
    float* evals    = (float*)d_ws + 64;
    float* partials = evals + n;
    int* hist    = (int*)(partials + NBS);
    int* offsets = hist + S;          // S+1 entries
    int* cursor  = offsets + S + 1;
    int* bucket  = cursor + S;

    hipMemsetAsync(hist, 0, (size_t)S * sizeof(int), stream);
    k_scores_hist<<<NBS, 256, 0, stream>>>(x, w, b, labels, evals, partials, hist, n);
    k_mid<<<1, 1024, 0, stream>>>(partials, NBS, inv_z, hist, offsets, cursor, S, n);
    k_fill<<<(n + 255) / 256, 256, 0, stream>>>(labels, cursor, bucket, n);
    k_gather<<<(S + 3) / 4, 256, 0, stream>>>(x, evals, bucket, offsets, inv_z, out, S);
}